// Round 1
// baseline (149.649 us; speedup 1.0000x reference)
//
#include <hip/hip_runtime.h>
#include <stdint.h>

typedef unsigned short u16;
typedef __attribute__((ext_vector_type(8))) short short8;
typedef __attribute__((ext_vector_type(4))) float f32x4;

#define NDIM 256
#define SDIM 128
#define DDIM 64
#define HDIM 32
#define PDIM 64

// fused-kernel tiling
#define IB 8            // i per workgroup
#define JB 4            // j per workgroup
#define TM 256          // IB*32 rows (m = i*32+h)
#define TN 128          // JB*32 cols (n = j*32+k)
#define ASP 72          // LDS pitch for A/B tiles (pad 64 -> 72 elems, 16B-aligned rows)
#define GPitch 1024     // LDS pitch for G (bf16), XOR-swizzled 16B granules

__device__ __forceinline__ u16 f2bf(float f) {
  union { float f; uint32_t u; } v; v.f = f;
  uint32_t r = v.u + 0x7fffu + ((v.u >> 16) & 1u);   // round-to-nearest-even
  return (u16)(r >> 16);
}

// ---------------- K1: LN + projections + transpose, Wo transpose ----------------
// grid 256 (one block per n), 256 threads: threads [0,128) handle a-proj for s=t,
// threads [128,256) handle b-proj for s=t-128. LN done by half 0, shared via LDS.
__global__ __launch_bounds__(256, 2) void k_pre(
    const float* __restrict__ msa, const float* __restrict__ mask,
    const float* __restrict__ gamma, const float* __restrict__ beta,
    const float* __restrict__ Wa, const float* __restrict__ ba,
    const float* __restrict__ Wb, const float* __restrict__ bb,
    const float* __restrict__ Wo,
    u16* __restrict__ a_t, u16* __restrict__ b_t, u16* __restrict__ W_t)
{
  __shared__ float xnL[128 * 65];   // pitch 65 to spread banks
  __shared__ float mrow[128];
  __shared__ u16 aT[HDIM * 128];
  __shared__ u16 bT[HDIM * 128];

  const int n = blockIdx.x;
  const int t = threadIdx.x;
  const int s = t & 127;
  const int half = t >> 7;

  const float mval = mask[s * NDIM + n];

  if (half == 0) {
    const float* xr = msa + (s * NDIM + n) * DDIM;
    float v[DDIM];
    float sum = 0.f;
    for (int d = 0; d < DDIM; d += 4) {
      const float4 q = *(const float4*)&xr[d];
      v[d] = q.x; v[d + 1] = q.y; v[d + 2] = q.z; v[d + 3] = q.w;
      sum += q.x + q.y + q.z + q.w;
    }
    const float mu = sum * (1.f / 64.f);
    float vs = 0.f;
    for (int d = 0; d < DDIM; ++d) { const float df = v[d] - mu; vs += df * df; }
    const float rs = rsqrtf(vs * (1.f / 64.f) + 1e-5f);
    for (int d = 0; d < DDIM; ++d)
      xnL[s * 65 + d] = (v[d] - mu) * rs * gamma[d] + beta[d];
    mrow[s] = mval;
  }
  __syncthreads();

  // denom_i = max(sum_s mask, 1): broadcast LDS reads, every thread computes it
  float dsum = 0.f;
  for (int ss = 0; ss < 128; ++ss) dsum += mrow[ss];
  const float dinv = 1.f / fmaxf(dsum, 1.f);

  const float* Wsel = half ? Wb : Wa;
  const float* bsel = half ? bb : ba;
  float accp[HDIM];
  for (int h = 0; h < HDIM; ++h) accp[h] = bsel[h];
  for (int d = 0; d < DDIM; ++d) {
    const float xv = xnL[s * 65 + d];
    for (int h = 0; h < HDIM; ++h) accp[h] += xv * Wsel[d * HDIM + h];  // Wsel uniform -> s_load
  }
  const float scale = half ? mval : mval * dinv;   // fold 1/denom[i] into a
  u16* dst = half ? bT : aT;
  for (int h = 0; h < HDIM; ++h) dst[h * 128 + s] = f2bf(accp[h] * scale);
  __syncthreads();

  // dump transposed tiles: rows ih = n*32+h, 128 contiguous s each (16B vectors)
  for (int it = 0; it < 2; ++it) {
    const int flat = it * 256 + t;   // 0..511 granules of 8
    *(short8*)&a_t[n * 4096 + flat * 8] = *(const short8*)&aT[flat * 8];
    *(short8*)&b_t[n * 4096 + flat * 8] = *(const short8*)&bT[flat * 8];
  }
  // W_t[p*1024 + hk] = bf16(Wo[hk*64 + p]); 65536 elems over 256 blocks x 256 thr
  {
    const int f = n * 256 + t;
    const int p = f >> 10, hk = f & 1023;
    W_t[f] = f2bf(Wo[hk * 64 + p]);
  }
}

// ---------------- K2: fused outer-product GEMM + Wo contraction ----------------
// grid (64 jTiles, 32 iTiles), 256 threads = 4 waves.
// Stage A: G[256m x 128n] = a_t-tile · b_t-tile^T over K=128 (two 64-chunks).
//          wave w owns m-slice [64w, 64w+64), all 128 n -> acc[4][8] f32x4.
// G -> LDS bf16 [rij=iloc*4+jloc][hk=h*32+k], XOR-swizzled granules, 64KB exact.
// Stage B: out[rij][p] = sum_hk G·W_t, M=32 K=1024 N=64; wave w owns p-tile w.
__global__ __launch_bounds__(256, 2) void k_fused(
    const u16* __restrict__ a_t, const u16* __restrict__ b_t,
    const u16* __restrict__ W_t, const float* __restrict__ bo,
    float* __restrict__ out)
{
  __shared__ char smem[65536];
  u16* As = (u16*)smem;                       // [TM][ASP]
  u16* Bs = (u16*)(smem + TM * ASP * 2);      // [TN][ASP]
  u16* Gs = (u16*)smem;                       // [32][GPitch], reused after barrier

  const int tid = threadIdx.x;
  const int lane = tid & 63;
  const int wv = tid >> 6;          // 0..3
  const int l15 = lane & 15;
  const int quad = lane >> 4;       // 0..3
  const int jTile = blockIdx.x;
  const int iTile = blockIdx.y;

  const u16* gA = a_t + iTile * TM * SDIM;   // contiguous 64KB slice
  const u16* gB = b_t + jTile * TN * SDIM;   // contiguous 32KB slice

  const f32x4 fz = {0.f, 0.f, 0.f, 0.f};
  f32x4 acc[4][8];
  for (int mt = 0; mt < 4; ++mt)
    for (int nt = 0; nt < 8; ++nt) acc[mt][nt] = fz;

  for (int ch = 0; ch < 2; ++ch) {
    __syncthreads();   // protect LDS from previous chunk's readers
    for (int it = 0; it < 8; ++it) {
      const int flat = it * 256 + tid;          // 2048 granules
      const int row = flat >> 3, kc = (flat & 7) * 8;
      *(short8*)&As[row * ASP + kc] = *(const short8*)&gA[row * SDIM + ch * 64 + kc];
    }
    for (int it = 0; it < 4; ++it) {
      const int flat = it * 256 + tid;          // 1024 granules
      const int row = flat >> 3, kc = (flat & 7) * 8;
      *(short8*)&Bs[row * ASP + kc] = *(const short8*)&gB[row * SDIM + ch * 64 + kc];
    }
    __syncthreads();
    for (int ks = 0; ks < 2; ++ks) {
      const int ko = ks * 32 + quad * 8;
      short8 af[4], bf[8];
      for (int mt = 0; mt < 4; ++mt)
        af[mt] = *(const short8*)&As[(wv * 64 + mt * 16 + l15) * ASP + ko];
      for (int nt = 0; nt < 8; ++nt)
        bf[nt] = *(const short8*)&Bs[(nt * 16 + l15) * ASP + ko];
      for (int mt = 0; mt < 4; ++mt)
        for (int nt = 0; nt < 8; ++nt)
          acc[mt][nt] = __builtin_amdgcn_mfma_f32_16x16x32_bf16(af[mt], bf[nt], acc[mt][nt], 0, 0, 0);
    }
  }
  __syncthreads();

  // accumulators -> Gs (bf16). C/D layout: row = quad*4+reg, col = l15 (m89-verified).
  for (int mt = 0; mt < 4; ++mt) {
    const int mbase = wv * 64 + mt * 16 + quad * 4;
    for (int nt = 0; nt < 8; ++nt) {
      const int n = nt * 16 + l15;
      for (int r = 0; r < 4; ++r) {
        const int m = mbase + r;
        const int rij = (m >> 5) * 4 + (n >> 5);          // i_loc*4 + j_loc
        const int hk = (m & 31) * 32 + (n & 31);          // h*32 + k
        const int g = hk >> 3;
        const int addr = rij * GPitch + ((g ^ (rij & 7)) << 3) + (hk & 7);
        Gs[addr] = f2bf(acc[mt][nt][r]);
      }
    }
  }
  __syncthreads();

  // Stage B: two 16-row m-tiles, wave's own 16-wide p-tile, 32 k-steps.
  f32x4 oacc0 = fz, oacc1 = fz;
  const int p0 = wv * 16;
  const u16* wrow = W_t + (p0 + l15) * 1024;
  const int sw = l15 & 7;                      // (16+l15)&7 == l15&7: same swizzle both rows
  const u16* g0 = Gs + l15 * GPitch;
  const u16* g1 = Gs + (16 + l15) * GPitch;
  for (int kk = 0; kk < 32; ++kk) {
    const int go = ((kk * 4 + quad) ^ sw) << 3;
    const short8 bw = *(const short8*)&wrow[kk * 32 + quad * 8];
    const short8 a0 = *(const short8*)&g0[go];
    const short8 a1 = *(const short8*)&g1[go];
    oacc0 = __builtin_amdgcn_mfma_f32_16x16x32_bf16(a0, bw, oacc0, 0, 0, 0);
    oacc1 = __builtin_amdgcn_mfma_f32_16x16x32_bf16(a1, bw, oacc1, 0, 0, 0);
  }
  const int p = p0 + l15;
  const float bop = bo[p];
  for (int r = 0; r < 4; ++r) {
    {
      const int rij = quad * 4 + r;
      const int iG = iTile * IB + (rij >> 2);
      const int jG = jTile * JB + (rij & 3);
      out[(iG * NDIM + jG) * PDIM + p] = oacc0[r] + bop;
    }
    {
      const int rij = 16 + quad * 4 + r;
      const int iG = iTile * IB + (rij >> 2);
      const int jG = jTile * JB + (rij & 3);
      out[(iG * NDIM + jG) * PDIM + p] = oacc1[r] + bop;
    }
  }
}

extern "C" void kernel_launch(void* const* d_in, const int* in_sizes, int n_in,
                              void* d_out, int out_size, void* d_ws, size_t ws_size,
                              hipStream_t stream) {
  const float* msa   = (const float*)d_in[0];
  const float* mask  = (const float*)d_in[1];
  const float* gamma = (const float*)d_in[2];
  const float* beta  = (const float*)d_in[3];
  const float* Wa    = (const float*)d_in[4];
  const float* ba    = (const float*)d_in[5];
  const float* Wb    = (const float*)d_in[6];
  const float* bb    = (const float*)d_in[7];
  const float* Wo    = (const float*)d_in[8];
  const float* bo    = (const float*)d_in[9];

  char* ws = (char*)d_ws;
  u16* a_t = (u16*)ws;                       // 2 MB: [8192 rows ih][128 s] bf16
  u16* b_t = (u16*)(ws + (2u << 20));        // 2 MB: [8192 rows jk][128 s] bf16
  u16* W_t = (u16*)(ws + (4u << 20));        // 128 KB: [64 p][1024 hk] bf16

  k_pre<<<dim3(256), dim3(256), 0, stream>>>(msa, mask, gamma, beta,
                                             Wa, ba, Wb, bb, Wo, a_t, b_t, W_t);
  k_fused<<<dim3(64, 32), dim3(256), 0, stream>>>(a_t, b_t, W_t, bo, (float*)d_out);
}